// Round 18
// baseline (442.881 us; speedup 1.0000x reference)
//
#include <hip/hip_runtime.h>
#include <stdint.h>

#define TL  2048
#define NB  4096
#define INSZ 8
#define HID 10
#define LOG2E 1.4426950408889634f
#define XS (NB * INSZ)            // floats per timestep slab
#define TSTEPS 16                 // timesteps per staged tile (1 KB DMA)
#define NBUF 4
#define NTILES (TL / TSTEPS)      // 128

typedef float v2f __attribute__((ext_vector_type(2)));

__device__ __forceinline__ float rcp_(float x)  { return __builtin_amdgcn_rcpf(x); }
__device__ __forceinline__ float exp2_(float x) { return __builtin_amdgcn_exp2f(x); }

// row_newbcast:K (DPP ctrl 0x150+K): every lane of each 16-lane row receives
// src from lane K of that row. old=0 + bound_ctrl=true + full masks -> folds
// to a single v_mov_b32_dpp (R13-proven).
template<int K> __device__ __forceinline__ float bcast16(float x) {
    return __int_as_float(__builtin_amdgcn_update_dpp(
        0, __float_as_int(x), 0x150 + K, 0xF, 0xF, true));
}

// One LSTM step, 32-lane gate-split: low half (lanes<32) computes rows (i,f),
// high half rows (g,o) of the SAME chain; both halves keep c,h redundantly.
// K-paired builtin pk math (R15/R17-proven lean body), batched rcp per half
// (2 exp2 + 1 rcp for both gates), permlane32_swap exchange (R9-verified:
// ret[0] = low-half's value on all lanes, ret[1] = high-half's).
// Weights pre-scaled by -log2e (sigmoid rows) / -2log2e (tanh row).
__device__ __forceinline__ void lstm_step(const float4& X0, const float4& X1,
        const v2f (&wxpA)[4], const v2f (&wxpB)[4],
        const v2f (&whpA)[5], const v2f (&whpB)[5],
        const v2f& bA, const v2f& bB, float mA, float oA,
        float& hst, float& cst) {
    const v2f xp0 = {X0.x, X0.y}, xp1 = {X0.z, X0.w};
    const v2f xp2 = {X1.x, X1.y}, xp3 = {X1.z, X1.w};
    // x-dot: 8 pk_fma; accumulators born from first FMA with C={bias,0}.
    v2f aA = __builtin_elementwise_fma(wxpA[0], xp0, bA);
    v2f aB = __builtin_elementwise_fma(wxpB[0], xp0, bB);
    aA = __builtin_elementwise_fma(wxpA[1], xp1, aA);
    aB = __builtin_elementwise_fma(wxpB[1], xp1, aB);
    aA = __builtin_elementwise_fma(wxpA[2], xp2, aA);
    aB = __builtin_elementwise_fma(wxpB[2], xp2, aB);
    aA = __builtin_elementwise_fma(wxpA[3], xp3, aA);
    aB = __builtin_elementwise_fma(wxpB[3], xp3, aB);
    // h-dot: 5 k-pairs = 10 DPP writes + 10 pk_fma.
#define HPAIR(P) do { \
        v2f hp; \
        hp.x = bcast16<2 * (P)>(hst); \
        hp.y = bcast16<2 * (P) + 1>(hst); \
        aA = __builtin_elementwise_fma(whpA[P], hp, aA); \
        aB = __builtin_elementwise_fma(whpB[P], hp, aB); \
    } while (0)
    HPAIR(0); HPAIR(1); HPAIR(2); HPAIR(3); HPAIR(4);
#undef HPAIR
    const float A = aA.x + aA.y;
    const float B = aB.x + aB.y;
    // Batched reciprocal over this half's two gates (overflow-safe).
    const float dA = 1.f + exp2_(A);
    const float dB = 1.f + exp2_(B);
    const float r  = rcp_(dA * dB);
    const float gA = fmaf(mA, r * dB, oA);   // i (low) / g (high): sig or tanh
    const float gB = r * dA;                 // f (low) / o (high): sigmoid
    const auto s1 = __builtin_amdgcn_permlane32_swap(
        __float_as_uint(gA), __float_as_uint(gA), false, false);
    const auto s2 = __builtin_amdgcn_permlane32_swap(
        __float_as_uint(gB), __float_as_uint(gB), false, false);
    const float iv = __uint_as_float(s1[0]);  // low half's gA = i
    const float gv = __uint_as_float(s1[1]);  // high half's gA = g
    const float fv = __uint_as_float(s2[0]);  // low half's gB = f
    const float ov = __uint_as_float(s2[1]);  // high half's gB = o
    cst = fmaf(fv, cst, iv * gv);
    const float th = fmaf(2.f, rcp_(1.f + exp2_(cst * (-2.f * LOG2E))), -1.f);
    hst = ov * th;
}

// One global_load_lds dwordx4: lane l's 16 B -> ldsbase + l*16 (wave-uniform
// base, linear lane layout). Consumers read through LDS (memory), so the
// "memory"-clobbered counted waits order them correctly (R7/R8-proven).
__device__ __forceinline__ void stage_tile(const float* gsrc_lane, float* ldsbase) {
    __builtin_amdgcn_global_load_lds(
        (const __attribute__((address_space(1))) void*)(uintptr_t)gsrc_lane,
        (__attribute__((address_space(3))) void*)(uint32_t)(uintptr_t)ldsbase,
        16, 0, 0);
}

template<int VM>
__device__ __forceinline__ void consume_tile(const float (&xb)[TSTEPS][2][INSZ],
        int c,
        const v2f (&wxpA)[4], const v2f (&wxpB)[4],
        const v2f (&whpA)[5], const v2f (&whpB)[5],
        const v2f& bA, const v2f& bB, float mA, float oA,
        float& hst, float& cst) {
    asm volatile("s_waitcnt vmcnt(%0)" :: "i"(VM) : "memory");
#pragma unroll
    for (int s = 0; s < TSTEPS; ++s) {
        const float4 xlo = *(const float4*)&xb[s][c][0];
        const float4 xhi = *(const float4*)&xb[s][c][4];
        lstm_step(xlo, xhi, wxpA, wxpB, whpA, whpB, bA, bB, mA, oA, hst, cst);
    }
}

// 32 lanes per chain (gate-split across the permlane32 boundary), 2 chains
// per wave, 2048 waves = 2 waves/SIMD: partner wave fills trans-latency and
// dep-chain stalls (the ~100 cy/step that 1-wave R15 cannot hide).
// waves_per_eu(2,2): pins occupancy target = actual -> no register squeeze
// (R10-proven: VGPR 128 resident at (2,2)).
__global__ void __attribute__((amdgpu_flat_work_group_size(64, 64)))
                __attribute__((amdgpu_waves_per_eu(2, 2)))
lstm_fused(
    const float* __restrict__ x,
    const float* __restrict__ h0,
    const float* __restrict__ c0,
    const float* __restrict__ Wih,
    const float* __restrict__ Whh,
    const float* __restrict__ bih,
    const float* __restrict__ bhh,
    const float* __restrict__ Wfc,
    const float* __restrict__ bfc,
    float* __restrict__ out)
{
    __shared__ float xbuf[NBUF][TSTEPS][2][INSZ];   // 4 KB

    const int lane = threadIdx.x;
    const int j16  = lane & 15;
    const int c    = (lane >> 4) & 1;               // chain within wave
    const int h2   = lane >> 5;                     // 0: (i,f) rows, 1: (g,o)
    const int n    = ((int)blockIdx.x << 1) + c;
    const int j    = (j16 < HID) ? j16 : 0;         // padding lanes mirror unit 0

    const int rowA = h2 ? 2 * HID + j : j;          // i or g
    const int rowB = rowA + HID;                    // f or o
    const float sA = h2 ? -2.f * LOG2E : -LOG2E;
    const float sB = -LOG2E;
    const float mA = h2 ? 2.f : 1.f;                // gateA affine: sig / tanh
    const float oA = h2 ? -1.f : 0.f;

    // K-paired weights (19 v2f = 38 regs), activation scale folded in.
    v2f wxpA[4], wxpB[4], whpA[5], whpB[5];
#pragma unroll
    for (int p = 0; p < 4; ++p) {
        wxpA[p] = (v2f){Wih[rowA * INSZ + 2 * p] * sA, Wih[rowA * INSZ + 2 * p + 1] * sA};
        wxpB[p] = (v2f){Wih[rowB * INSZ + 2 * p] * sB, Wih[rowB * INSZ + 2 * p + 1] * sB};
    }
#pragma unroll
    for (int p = 0; p < 5; ++p) {
        whpA[p] = (v2f){Whh[rowA * HID + 2 * p] * sA, Whh[rowA * HID + 2 * p + 1] * sA};
        whpB[p] = (v2f){Whh[rowB * HID + 2 * p] * sB, Whh[rowB * HID + 2 * p + 1] * sB};
    }
    const v2f bA = (v2f){(bih[rowA] + bhh[rowA]) * sA, 0.f};
    const v2f bB = (v2f){(bih[rowB] + bhh[rowB]) * sB, 0.f};

    float cst = c0[n * HID + j];
    float hst = h0[n * HID + j];

    // Staging source (R8-proven): lane l covers (ts = l>>2, chain = (l>>1)&1,
    // half = l&1) -> LDS byte l*16 matches xbuf[..][ts][ch][half*4..+3].
    const int ts = lane >> 2, ch = (lane >> 1) & 1, hf = lane & 1;
    const float* gl = x + (size_t)ts * XS
                        + (size_t)((((int)blockIdx.x << 1) + ch) * INSZ + hf * 4);

    asm volatile("" ::: "memory");
#pragma unroll
    for (int b = 0; b < NBUF; ++b) {
        stage_tile(gl, &xbuf[b][0][0][0]);
        asm volatile("" ::: "memory");
        gl += (size_t)TSTEPS * XS;
    }

    // Main: counted vmcnt(3) completes exactly the oldest (this tile's) DMA;
    // lgkmcnt(0) ensures the buffer's ds_reads retired before its rewrite.
    for (int tile = 0; tile < NTILES - NBUF; ++tile) {
        const int b = tile & (NBUF - 1);
        consume_tile<3>(xbuf[b], c, wxpA, wxpB, whpA, whpB, bA, bB, mA, oA, hst, cst);
        asm volatile("s_waitcnt lgkmcnt(0)" ::: "memory");
        stage_tile(gl, &xbuf[b][0][0][0]);
        asm volatile("" ::: "memory");
        gl += (size_t)TSTEPS * XS;
    }
    // Drain: descending counted waits, no reissue.
    consume_tile<3>(xbuf[0], c, wxpA, wxpB, whpA, whpB, bA, bB, mA, oA, hst, cst);
    consume_tile<2>(xbuf[1], c, wxpA, wxpB, whpA, whpB, bA, bB, mA, oA, hst, cst);
    consume_tile<1>(xbuf[2], c, wxpA, wxpB, whpA, whpB, bA, bB, mA, oA, hst, cst);
    consume_tile<0>(xbuf[3], c, wxpA, wxpB, whpA, whpB, bA, bB, mA, oA, hst, cst);

    // Epilogue: each 16-row holds its chain's full h; collect via DPP.
    float hv[HID];
    hv[0] = bcast16<0>(hst); hv[1] = bcast16<1>(hst);
    hv[2] = bcast16<2>(hst); hv[3] = bcast16<3>(hst);
    hv[4] = bcast16<4>(hst); hv[5] = bcast16<5>(hst);
    hv[6] = bcast16<6>(hst); hv[7] = bcast16<7>(hst);
    hv[8] = bcast16<8>(hst); hv[9] = bcast16<9>(hst);

    if (h2 == 0 && j16 < INSZ) {
        float acc = bfc[j16];
#pragma unroll
        for (int k = 0; k < HID; ++k) acc = fmaf(Wfc[j16 * HID + k], hv[k], acc);
        out[n * INSZ + j16] = acc;
    }
    if (h2 == 0 && j16 < HID) {
        out[NB * INSZ + n * HID + j16] = hst;
    }
    if (h2 == 1 && j16 < HID) {
        out[NB * INSZ + NB * HID + n * HID + j16] = cst;
    }
}

extern "C" void kernel_launch(void* const* d_in, const int* in_sizes, int n_in,
                              void* d_out, int out_size, void* d_ws, size_t ws_size,
                              hipStream_t stream) {
    const float* x   = (const float*)d_in[0];
    const float* h0  = (const float*)d_in[1];
    const float* c0  = (const float*)d_in[2];
    const float* Wih = (const float*)d_in[3];
    const float* Whh = (const float*)d_in[4];
    const float* bih = (const float*)d_in[5];
    const float* bhh = (const float*)d_in[6];
    const float* Wfc = (const float*)d_in[7];
    const float* bfc = (const float*)d_in[8];
    float* out = (float*)d_out;

    lstm_fused<<<NB / 2, 64, 0, stream>>>(x, h0, c0, Wih, Whh, bih, bhh, Wfc, bfc, out);
}

// Round 19
// 392.990 us; speedup vs baseline: 1.1270x; 1.1270x over previous
//
#include <hip/hip_runtime.h>
#include <stdint.h>

#define TL  2048
#define NB  4096
#define INSZ 8
#define HID 10
#define LOG2E 1.4426950408889634f
#define XS (NB * INSZ)            // floats per timestep slab
#define TSTEPS 8                  // timesteps per staged tile (1 KB DMA)
#define NBUF 4
#define NTILES (TL / TSTEPS)      // 256

typedef float v2f __attribute__((ext_vector_type(2)));

__device__ __forceinline__ float rcp_(float x)  { return __builtin_amdgcn_rcpf(x); }
__device__ __forceinline__ float exp2_(float x) { return __builtin_amdgcn_exp2f(x); }

// row_newbcast:K (DPP ctrl 0x150+K): every lane of each 16-lane row receives
// src from lane K of that row. old=0 + bound_ctrl=true + full masks -> folds
// to a single v_mov_b32_dpp (R13-proven).
template<int K> __device__ __forceinline__ float bcast16(float x) {
    return __int_as_float(__builtin_amdgcn_update_dpp(
        0, __float_as_int(x), 0x150 + K, 0xF, 0xF, true));
}

// x-projection for one step: 16 pk_fma, K-paired (pairs alias float4 halves),
// accumulators born from first FMA with C={bias,0}. Independent of h — this
// is the work that pipelines into the previous step's activation shadow.
__device__ __forceinline__ void xdot(const float4& X0, const float4& X1,
        const v2f (&wxp)[4][4], const v2f (&bp)[4], v2f (&ax)[4]) {
    const v2f xp0 = {X0.x, X0.y}, xp1 = {X0.z, X0.w};
    const v2f xp2 = {X1.x, X1.y}, xp3 = {X1.z, X1.w};
#pragma unroll
    for (int g = 0; g < 4; ++g) {
        ax[g] = __builtin_elementwise_fma(wxp[g][0], xp0, bp[g]);
        ax[g] = __builtin_elementwise_fma(wxp[g][1], xp1, ax[g]);
        ax[g] = __builtin_elementwise_fma(wxp[g][2], xp2, ax[g]);
        ax[g] = __builtin_elementwise_fma(wxp[g][3], xp3, ax[g]);
    }
}

// h-dot + activations for one step, given the precomputed x-projection.
// Weights pre-scaled by -log2e (i,f,o) / -2log2e (g); ONE batched rcp serves
// all 4 gate activations (overflow-safe: each d <= ~2^25).
__device__ __forceinline__ void hstep(const v2f (&ax)[4],
        const v2f (&whp)[4][5], float& hst, float& cst) {
    v2f a0 = ax[0], a1 = ax[1], a2 = ax[2], a3 = ax[3];
#define HPAIR(P) do { \
        v2f hp; \
        hp.x = bcast16<2 * (P)>(hst); \
        hp.y = bcast16<2 * (P) + 1>(hst); \
        a0 = __builtin_elementwise_fma(whp[0][P], hp, a0); \
        a1 = __builtin_elementwise_fma(whp[1][P], hp, a1); \
        a2 = __builtin_elementwise_fma(whp[2][P], hp, a2); \
        a3 = __builtin_elementwise_fma(whp[3][P], hp, a3); \
    } while (0)
    HPAIR(0); HPAIR(1); HPAIR(2); HPAIR(3); HPAIR(4);
#undef HPAIR
    const float A0 = a0.x + a0.y;
    const float A1 = a1.x + a1.y;
    const float A2 = a2.x + a2.y;
    const float A3 = a3.x + a3.y;
    const float d0 = 1.f + exp2_(A0);
    const float d1 = 1.f + exp2_(A1);
    const float d2 = 1.f + exp2_(A2);
    const float d3 = 1.f + exp2_(A3);
    const float p01 = d0 * d1, p23 = d2 * d3;
    const float r   = rcp_(p01 * p23);
    const float r01 = r * p23, r23 = r * p01;
    const float ig = r01 * d1;                    // 1/d0 = sigmoid(i)
    const float fg = r01 * d0;                    // 1/d1 = sigmoid(f)
    const float gg = fmaf(2.f, r23 * d3, -1.f);   // 2/d2-1 = tanh(g)
    const float og = r23 * d2;                    // 1/d3 = sigmoid(o)
    cst = fmaf(fg, cst, ig * gg);
    const float th = fmaf(2.f, rcp_(1.f + exp2_(cst * (-2.f * LOG2E))), -1.f);
    hst = og * th;
}

// One global_load_lds dwordx4: lane l's 16 B -> ldsbase + l*16 (wave-uniform
// base, linear lane layout). Consumers read through LDS (memory), so the
// "memory"-clobbered counted waits order them correctly (R7-proven).
__device__ __forceinline__ void stage_tile(const float* gsrc_lane, float* ldsbase) {
    __builtin_amdgcn_global_load_lds(
        (const __attribute__((address_space(1))) void*)(uintptr_t)gsrc_lane,
        (__attribute__((address_space(3))) void*)(uint32_t)(uintptr_t)ldsbase,
        16, 0, 0);
}

// Software-pipelined tile: at step s, ax already holds step s's x-projection;
// we issue step s+1's LDS reads + x-dot BETWEEN s's h-dot and s's activation
// consumption point, so the 16 independent pk_fma fill the serial exp2/rcp
// shadow (the ~100 cy/step the 1-wave form cannot otherwise hide).
template<int VM>
__device__ __forceinline__ void consume_tile(const float (&xb)[TSTEPS][4][INSZ],
        int grp, const v2f (&wxp)[4][4], const v2f (&whp)[4][5],
        const v2f (&bp)[4], v2f (&ax)[4], float& hst, float& cst) {
    asm volatile("s_waitcnt vmcnt(%0)" :: "i"(VM) : "memory");
#pragma unroll
    for (int s = 0; s < TSTEPS; ++s) {
        v2f axn[4];
        if (s + 1 < TSTEPS) {
            const float4 xlo = *(const float4*)&xb[s + 1][grp][0];
            const float4 xhi = *(const float4*)&xb[s + 1][grp][4];
            xdot(xlo, xhi, wxp, bp, axn);   // independent: fills s's act shadow
        }
        hstep(ax, whp, hst, cst);
#pragma unroll
        for (int g = 0; g < 4; ++g) ax[g] = axn[g];
    }
}

// 16 lanes per chain, 4 chains per wave, 1024 waves = 1 wave/SIMD.
// Lane j16<10 owns hidden unit j: gate rows {j,10+j,20+j,30+j}.
// h exchanged via DPP row_newbcast. x staged via 4-deep LDS DMA pipeline.
// waves_per_eu(1,1): max=1 disarms the occupancy-driven register squeeze
// (R14-proven: weights resident).
__global__ void __attribute__((amdgpu_flat_work_group_size(64, 64)))
                __attribute__((amdgpu_waves_per_eu(1, 1)))
lstm_fused(
    const float* __restrict__ x,
    const float* __restrict__ h0,
    const float* __restrict__ c0,
    const float* __restrict__ Wih,
    const float* __restrict__ Whh,
    const float* __restrict__ bih,
    const float* __restrict__ bhh,
    const float* __restrict__ Wfc,
    const float* __restrict__ bfc,
    float* __restrict__ out)
{
    __shared__ float xbuf[NBUF][TSTEPS][4][INSZ];   // 4 KB

    const int lane = threadIdx.x;
    const int j16  = lane & 15;
    const int grp  = lane >> 4;
    const int n    = ((int)blockIdx.x << 2) + grp;
    const int j    = (j16 < HID) ? j16 : 0;   // clamp padding lanes
    const int src  = lane & 48;               // 16-lane group base

    // K-paired weights (76 regs), activation scale folded in.
    v2f wxp[4][4], whp[4][5], bp[4];
#pragma unroll
    for (int g = 0; g < 4; ++g) {
        const int row = g * HID + j;
        const float s = (g == 2 ? -2.f : -1.f) * LOG2E;
#pragma unroll
        for (int p = 0; p < 4; ++p)
            wxp[g][p] = (v2f){Wih[row * INSZ + 2 * p] * s,
                              Wih[row * INSZ + 2 * p + 1] * s};
#pragma unroll
        for (int p = 0; p < 5; ++p)
            whp[g][p] = (v2f){Whh[row * HID + 2 * p] * s,
                              Whh[row * HID + 2 * p + 1] * s};
        bp[g] = (v2f){(bih[row] + bhh[row]) * s, 0.f};
    }

    float cst = c0[n * HID + j];
    float hst = h0[n * HID + j];

    // Per-lane staging source: lane l covers (ts = l>>3, chain = (l>>1)&3,
    // half = l&1) -> LDS byte l*16 matches xbuf[..][ts][chain][half*4..+3].
    const int ts = lane >> 3, ch = (lane >> 1) & 3, hf = lane & 1;
    const float* gl = x + (size_t)ts * XS
                        + (size_t)((((int)blockIdx.x << 2) + ch) * INSZ + hf * 4);

    asm volatile("" ::: "memory");
#pragma unroll
    for (int b = 0; b < NBUF; ++b) {
        stage_tile(gl, &xbuf[b][0][0][0]);
        asm volatile("" ::: "memory");
        gl += (size_t)TSTEPS * XS;
    }

    // Prime the step pipeline: step 0's x-dot after tile 0 lands.
    v2f ax[4];
    asm volatile("s_waitcnt vmcnt(%0)" :: "i"(NBUF - 1) : "memory");
    {
        const float4 xlo = *(const float4*)&xbuf[0][0][grp][0];
        const float4 xhi = *(const float4*)&xbuf[0][0][grp][4];
        xdot(xlo, xhi, wxp, bp, ax);
    }

    // Main: counted vmcnt(3) completes exactly the oldest (this tile's) DMA;
    // lgkmcnt(0) ensures the buffer's ds_reads retired before its rewrite.
    for (int tile = 0; tile < NTILES - NBUF; ++tile) {
        const int b = tile & (NBUF - 1);
        consume_tile<3>(xbuf[b], grp, wxp, whp, bp, ax, hst, cst);
        asm volatile("s_waitcnt lgkmcnt(0)" ::: "memory");
        stage_tile(gl, &xbuf[b][0][0][0]);
        asm volatile("" ::: "memory");
        gl += (size_t)TSTEPS * XS;
        // prime next tile's step 0 (its DMA is NBUF-1 deep in the queue)
        const int nb = (tile + 1) & (NBUF - 1);
        asm volatile("s_waitcnt vmcnt(%0)" :: "i"(NBUF - 1) : "memory");
        const float4 xlo = *(const float4*)&xbuf[nb][0][grp][0];
        const float4 xhi = *(const float4*)&xbuf[nb][0][grp][4];
        xdot(xlo, xhi, wxp, bp, ax);
    }
    // Drain: descending counted waits, no reissue; prime each next tile.
#pragma unroll
    for (int d = 0; d < NBUF; ++d) {
        const int b = (NTILES - NBUF + d) & (NBUF - 1);
        consume_tile<0>(xbuf[b], grp, wxp, whp, bp, ax, hst, cst);
        if (d + 1 < NBUF) {
            const int nb = (b + 1) & (NBUF - 1);
            const float4 xlo = *(const float4*)&xbuf[nb][0][grp][0];
            const float4 xhi = *(const float4*)&xbuf[nb][0][grp][4];
            xdot(xlo, xhi, wxp, bp, ax);
        }
    }

    // epilogue (one-time, DS shuffles fine here): y = h @ W_fc.T + b_fc; dump h, c
    float hv[HID];
#pragma unroll
    for (int k = 0; k < HID; ++k) hv[k] = __shfl(hst, src + k, 64);

    if (j16 < INSZ) {
        float acc = bfc[j16];
#pragma unroll
        for (int k = 0; k < HID; ++k) acc = fmaf(Wfc[j16 * HID + k], hv[k], acc);
        out[n * INSZ + j16] = acc;
    }
    if (j16 < HID) {
        out[NB * INSZ + n * HID + j16] = hst;
        out[NB * INSZ + NB * HID + n * HID + j16] = cst;
    }
}

extern "C" void kernel_launch(void* const* d_in, const int* in_sizes, int n_in,
                              void* d_out, int out_size, void* d_ws, size_t ws_size,
                              hipStream_t stream) {
    const float* x   = (const float*)d_in[0];
    const float* h0  = (const float*)d_in[1];
    const float* c0  = (const float*)d_in[2];
    const float* Wih = (const float*)d_in[3];
    const float* Whh = (const float*)d_in[4];
    const float* bih = (const float*)d_in[5];
    const float* bhh = (const float*)d_in[6];
    const float* Wfc = (const float*)d_in[7];
    const float* bfc = (const float*)d_in[8];
    float* out = (float*)d_out;

    lstm_fused<<<NB / 4, 64, 0, stream>>>(x, h0, c0, Wih, Whh, bih, bhh, Wfc, bfc, out);
}